// Round 1
// baseline (3567.530 us; speedup 1.0000x reference)
//
#include <hip/hip_runtime.h>

// ---------------------------------------------------------------------------
// SpectralGatingNetwork forward on MI355X (gfx950).
// B=2, T=2048, V=32000, D=1024, F=256, NL=6, LAT=64.
// Strategy: fp32 residual stream; all big GEMMs via f16 MFMA (16x16x32) with
// fp32 accumulate and fused epilogues; exact 3-phase chunked scan for the
// complex linear recurrence.
// ---------------------------------------------------------------------------

#define BB 2
#define TT 2048
#define VV 32000
#define DD 1024
#define FF 256
#define NLAYER 6
#define LATD 64
#define RR (BB*TT)          // 4096 rows

typedef _Float16 half8 __attribute__((ext_vector_type(8)));
typedef _Float16 half4 __attribute__((ext_vector_type(4)));
typedef float floatx4 __attribute__((ext_vector_type(4)));

enum { EP_F32 = 0, EP_GATE, EP_DECAY, EP_OGATE, EP_GELU16, EP_ADDH };

__device__ __forceinline__ float sigmoidf_(float x) { return 1.0f / (1.0f + expf(-x)); }
__device__ __forceinline__ float gelu_exact(float x) {
  return 0.5f * x * (1.0f + erff(x * 0.70710678118654752f));
}

// ---------------- fp32 -> f16 convert (vectorized by 4) ----------------
__global__ void cvt_kernel(const float* __restrict__ src, _Float16* __restrict__ dst, int n4) {
  int i = blockIdx.x * blockDim.x + threadIdx.x;
  if (i < n4) {
    float4 v = ((const float4*)src)[i];
    half4 o;
    o.x = (_Float16)v.x; o.y = (_Float16)v.y; o.z = (_Float16)v.z; o.w = (_Float16)v.w;
    ((half4*)dst)[i] = o;
  }
}

// ---------------- embedding lookup: h[m,:] = emb[x[m],:] ----------------
__global__ void embed_kernel(const int* __restrict__ x, const float* __restrict__ emb,
                             float* __restrict__ h) {
  int m = blockIdx.x;
  int t = threadIdx.x;
  long row = x[m];
  float4 v = ((const float4*)(emb + row * DD))[t];
  ((float4*)(h + (long)m * DD))[t] = v;
}

// ---------------- LayerNorm over D=1024, optional addend, f16 out ----------------
__global__ void ln_kernel(const float* __restrict__ x, const float* __restrict__ add,
                          const float* __restrict__ g, const float* __restrict__ b,
                          _Float16* __restrict__ out) {
  int m = blockIdx.x;
  int t = threadIdx.x;
  float4 v = ((const float4*)(x + (long)m * DD))[t];
  if (add) {
    float4 a = ((const float4*)(add + (long)m * DD))[t];
    v.x += a.x; v.y += a.y; v.z += a.z; v.w += a.w;
  }
  float s  = v.x + v.y + v.z + v.w;
  float s2 = v.x * v.x + v.y * v.y + v.z * v.z + v.w * v.w;
  #pragma unroll
  for (int off = 32; off > 0; off >>= 1) {
    s  += __shfl_down(s, off);
    s2 += __shfl_down(s2, off);
  }
  __shared__ float ss[4], ss2[4];
  __shared__ float mean_s, rstd_s;
  int lane = t & 63, wv = t >> 6;
  if (lane == 0) { ss[wv] = s; ss2[wv] = s2; }
  __syncthreads();
  if (t == 0) {
    float S = ss[0] + ss[1] + ss[2] + ss[3];
    float S2 = ss2[0] + ss2[1] + ss2[2] + ss2[3];
    float mean = S * (1.0f / DD);
    float var = S2 * (1.0f / DD) - mean * mean;
    mean_s = mean;
    rstd_s = rsqrtf(var + 1e-5f);
  }
  __syncthreads();
  float mean = mean_s, rstd = rstd_s;
  float4 gg = ((const float4*)g)[t];
  float4 bb = ((const float4*)b)[t];
  half4 o;
  o.x = (_Float16)((v.x - mean) * rstd * gg.x + bb.x);
  o.y = (_Float16)((v.y - mean) * rstd * gg.y + bb.y);
  o.z = (_Float16)((v.z - mean) * rstd * gg.z + bb.z);
  o.w = (_Float16)((v.w - mean) * rstd * gg.w + bb.w);
  ((half4*)(out + (long)m * DD))[t] = o;
}

// ---------------- GEMM: Y(M,N) = A(M,K) @ W(N,K)^T, f16 in, fp32 acc ----------------
// 128x128 tile, BK=64, 4 waves each computing 64x64 via 4x4 MFMA 16x16x32_f16.
// LDS rows padded to 72 f16 (144B) -> <=2-way bank conflicts (free).
template <int EP>
__launch_bounds__(256)
__global__ void gemm_nt(const _Float16* __restrict__ A, const _Float16* __restrict__ W,
                        int M, int N, int K,
                        const float* __restrict__ bias,
                        float* __restrict__ out0, float* __restrict__ out1,
                        const float* __restrict__ auxf,
                        const _Float16* __restrict__ auxh,
                        _Float16* __restrict__ outh) {
  __shared__ _Float16 As[128 * 72];
  __shared__ _Float16 Ws[128 * 72];
  int tid = threadIdx.x;
  int lane = tid & 63, w = tid >> 6;
  int wm = w & 1, wn = w >> 1;
  long m0 = (long)blockIdx.y * 128, n0 = (long)blockIdx.x * 128;

  floatx4 acc[4][4] = {};

  for (long kb = 0; kb < K; kb += 64) {
    #pragma unroll
    for (int it = 0; it < 4; ++it) {
      int i = tid + it * 256;          // 0..1023
      int row = i >> 3;
      int col8 = (i & 7) * 8;
      uint4 va = *(const uint4*)(A + (m0 + row) * (long)K + kb + col8);
      uint4 vw = *(const uint4*)(W + (n0 + row) * (long)K + kb + col8);
      *(uint4*)(&As[row * 72 + col8]) = va;
      *(uint4*)(&Ws[row * 72 + col8]) = vw;
    }
    __syncthreads();
    #pragma unroll
    for (int ks = 0; ks < 2; ++ks) {
      half8 af[4], bf[4];
      int kofs = ks * 32 + (lane >> 4) * 8;
      #pragma unroll
      for (int at = 0; at < 4; ++at)
        af[at] = *(const half8*)(&As[(wm * 64 + at * 16 + (lane & 15)) * 72 + kofs]);
      #pragma unroll
      for (int bt = 0; bt < 4; ++bt)
        bf[bt] = *(const half8*)(&Ws[(wn * 64 + bt * 16 + (lane & 15)) * 72 + kofs]);
      #pragma unroll
      for (int at = 0; at < 4; ++at)
        #pragma unroll
        for (int bt = 0; bt < 4; ++bt)
          acc[at][bt] = __builtin_amdgcn_mfma_f32_16x16x32_f16(af[at], bf[bt], acc[at][bt], 0, 0, 0);
    }
    __syncthreads();
  }

  // Epilogue. C/D layout: col = lane&15, row = (lane>>4)*4 + reg (verified m89/m91).
  #pragma unroll
  for (int at = 0; at < 4; ++at) {
    #pragma unroll
    for (int bt = 0; bt < 4; ++bt) {
      #pragma unroll
      for (int rr = 0; rr < 4; ++rr) {
        long row = m0 + wm * 64 + at * 16 + (lane >> 4) * 4 + rr;
        long col = n0 + wn * 64 + bt * 16 + (lane & 15);
        float v = acc[at][bt][rr];
        if (bias) v += bias[col];
        long idx = row * (long)N + col;
        if constexpr (EP == EP_F32) {
          out0[idx] = v;
        } else if constexpr (EP == EP_GATE) {
          float s = sigmoidf_(v);
          outh[idx] = (_Float16)((float)auxh[idx] * s);
        } else if constexpr (EP == EP_DECAY) {
          float s = sigmoidf_(v);
          float om = auxf[col] * 0.1f;
          out0[idx] = s * cosf(om);
          out1[idx] = s * sinf(om);
        } else if constexpr (EP == EP_OGATE) {
          float s = sigmoidf_(v);
          out0[idx] += auxf[idx] * s;
        } else if constexpr (EP == EP_GELU16) {
          outh[idx] = (_Float16)gelu_exact(v);
        } else if constexpr (EP == EP_ADDH) {
          out0[idx] += v;
        }
      }
    }
  }
}

// ---------------- scan phase 1: per (b,f,chunk) local scan of 64 steps ----------------
// y_t = a_t*y_{t-1} + u_t (complex); also cumulative product A_t of a's.
__global__ void scan_phase1(const float* __restrict__ ar, const float* __restrict__ ai,
                            const float* __restrict__ sp,
                            float* __restrict__ Ar, float* __restrict__ Ai,
                            float* __restrict__ Yr, float* __restrict__ Yi) {
  int gid = blockIdx.x * 256 + threadIdx.x;   // 0..16383
  int f = gid & 255;
  int c = (gid >> 8) & 31;
  int b = gid >> 13;
  float car = 1.0f, cai = 0.0f, yr = 0.0f, yi = 0.0f;
  int base_t = b * TT + c * 64;
  for (int tl = 0; tl < 64; ++tl) {
    long m = base_t + tl;
    float a_r = ar[m * FF + f], a_i = ai[m * FF + f];
    float u_r = sp[m * (2 * FF) + f], u_i = sp[m * (2 * FF) + FF + f];
    float nyr = a_r * yr - a_i * yi + u_r;
    float nyi = a_r * yi + a_i * yr + u_i;
    float nar = a_r * car - a_i * cai;
    float nai = a_r * cai + a_i * car;
    yr = nyr; yi = nyi; car = nar; cai = nai;
    Ar[m * FF + f] = car; Ai[m * FF + f] = cai;
    Yr[m * FF + f] = yr;  Yi[m * FF + f] = yi;
  }
}

// ---------------- scan phase 2: sequential carry over 32 chunks per channel ----------------
__global__ void scan_phase2(const float* __restrict__ Ar, const float* __restrict__ Ai,
                            const float* __restrict__ Yr, const float* __restrict__ Yi,
                            float* __restrict__ cr, float* __restrict__ ci) {
  int gid = blockIdx.x * 256 + threadIdx.x;   // 0..511
  int f = gid & 255;
  int b = gid >> 8;
  float ur = 0.0f, ui = 0.0f;
  for (int c = 0; c < 32; ++c) {
    cr[(c * 2 + b) * 256 + f] = ur;           // exclusive carry for this chunk
    ci[(c * 2 + b) * 256 + f] = ui;
    long m = (long)b * TT + c * 64 + 63;      // chunk composite = its last element
    float A_r = Ar[m * FF + f], A_i = Ai[m * FF + f];
    float U_r = Yr[m * FF + f], U_i = Yi[m * FF + f];
    float nur = A_r * ur - A_i * ui + U_r;
    float nui = A_r * ui + A_i * ur + U_i;
    ur = nur; ui = nui;
  }
}

// ---------------- scan phase 3: apply carry, emit y16 in concat [y_r | y_i] layout ------
__global__ void scan_phase3(const float* __restrict__ Ar, const float* __restrict__ Ai,
                            const float* __restrict__ Yr, const float* __restrict__ Yi,
                            const float* __restrict__ cr, const float* __restrict__ ci,
                            _Float16* __restrict__ y16) {
  long m = blockIdx.x;                        // 0..4095
  int f = threadIdx.x;                        // 0..255
  int b = (int)(m >> 11);
  int t = (int)(m & 2047);
  int c = t >> 6;
  float u1r = cr[(c * 2 + b) * 256 + f];
  float u1i = ci[(c * 2 + b) * 256 + f];
  float A_r = Ar[m * FF + f], A_i = Ai[m * FF + f];
  float yr = A_r * u1r - A_i * u1i + Yr[m * FF + f];
  float yi = A_r * u1i + A_i * u1r + Yi[m * FF + f];
  y16[m * (2 * FF) + f] = (_Float16)yr;
  y16[m * (2 * FF) + FF + f] = (_Float16)yi;
}

// ---------------- dec_W transpose (1024x64 -> 64x1024) ----------------
__global__ void transpose_decW(const float* __restrict__ decW, float* __restrict__ decWT) {
  int i = blockIdx.x * 256 + threadIdx.x;     // 0..65535
  int d = i >> 6, l = i & 63;
  decWT[l * DD + d] = decW[i];
}

// ---------------- concept = gelu(mu @ dec_W^T + dec_b), K=64 ----------------
__global__ void dec_kernel(const float* __restrict__ params, const float* __restrict__ decWT,
                           const float* __restrict__ decb, float* __restrict__ concept) {
  __shared__ float smu[64];
  long m = blockIdx.x;
  int t = threadIdx.x;
  if (t < 64) smu[t] = params[m * 128 + t];
  __syncthreads();
  float acc[4] = {0.f, 0.f, 0.f, 0.f};
  for (int l = 0; l < 64; ++l) {
    float mu = smu[l];
    #pragma unroll
    for (int j = 0; j < 4; ++j) acc[j] += mu * decWT[l * DD + j * 256 + t];
  }
  #pragma unroll
  for (int j = 0; j < 4; ++j) {
    int d = j * 256 + t;
    float v = acc[j] + decb[d];
    concept[m * DD + d] = gelu_exact(v);
  }
}

// ---------------- KL sum reduction ----------------
__global__ void kl_kernel(const float* __restrict__ params, float* __restrict__ klsum) {
  int idx0 = blockIdx.x * blockDim.x + threadIdx.x;
  float local = 0.0f;
  for (int idx = idx0; idx < RR * LATD; idx += gridDim.x * blockDim.x) {
    long m = idx >> 6;
    int l = idx & 63;
    float mu = params[m * 128 + l];
    float lv = params[m * 128 + 64 + l];
    local += -0.5f * (1.0f + lv - mu * mu - expf(lv));
  }
  #pragma unroll
  for (int off = 32; off > 0; off >>= 1) local += __shfl_down(local, off);
  __shared__ float ss[4];
  int lane = threadIdx.x & 63, wv = threadIdx.x >> 6;
  if (lane == 0) ss[wv] = local;
  __syncthreads();
  if (threadIdx.x == 0) atomicAdd(klsum, ss[0] + ss[1] + ss[2] + ss[3]);
}

__global__ void fin_kernel(const float* __restrict__ klsum, float* __restrict__ out) {
  float mean = klsum[0] * (1.0f / (RR * LATD));
  out[0] = 0.01f * fmaxf(mean, 0.05f);
}

// ---------------------------------------------------------------------------
extern "C" void kernel_launch(void* const* d_in, const int* in_sizes, int n_in,
                              void* d_out, int out_size, void* d_ws, size_t ws_size,
                              hipStream_t stream) {
  const int*   x         = (const int*)d_in[0];
  const float* emb       = (const float*)d_in[1];
  const float* freq      = (const float*)d_in[2];
  const float* decay_W   = (const float*)d_in[3];
  const float* decay_b   = (const float*)d_in[4];
  const float* spec_in_W = (const float*)d_in[5];
  const float* spec_out_W= (const float*)d_in[6];
  const float* norm1_g   = (const float*)d_in[7];
  const float* norm1_b   = (const float*)d_in[8];
  const float* gate_W    = (const float*)d_in[9];
  const float* gate_b    = (const float*)d_in[10];
  const float* ogate_W   = (const float*)d_in[11];
  const float* ogate_b   = (const float*)d_in[12];
  const float* ffn_g     = (const float*)d_in[13];
  const float* ffn_b     = (const float*)d_in[14];
  const float* ffn_W1    = (const float*)d_in[15];
  const float* ffn_b1    = (const float*)d_in[16];
  const float* ffn_W2    = (const float*)d_in[17];
  const float* ffn_b2    = (const float*)d_in[18];
  const float* vib_g     = (const float*)d_in[19];
  const float* vib_b     = (const float*)d_in[20];
  const float* enc_W     = (const float*)d_in[21];
  const float* enc_b     = (const float*)d_in[22];
  const float* dec_W     = (const float*)d_in[23];
  const float* dec_b     = (const float*)d_in[24];
  const float* normf_g   = (const float*)d_in[25];
  const float* normf_b   = (const float*)d_in[26];
  float* logits = (float*)d_out;

  char* base = (char*)d_ws;
  size_t off = 0;
  auto alloc = [&](size_t bytes) -> void* {
    void* p = base + off;
    off = (off + bytes + 255) & ~(size_t)255;
    return p;
  };

  _Float16* emb16     = (_Float16*)alloc((size_t)VV * DD * 2);
  _Float16* enc16     = (_Float16*)alloc((size_t)128 * DD * 2);
  _Float16* gate16    = (_Float16*)alloc((size_t)DD * DD * 2);
  _Float16* ogate16   = (_Float16*)alloc((size_t)DD * DD * 2);
  _Float16* decay16   = (_Float16*)alloc((size_t)FF * DD * 2);
  _Float16* specin16  = (_Float16*)alloc((size_t)2 * FF * DD * 2);
  _Float16* specout16 = (_Float16*)alloc((size_t)DD * 2 * FF * 2);
  _Float16* ffn116    = (_Float16*)alloc((size_t)4 * DD * DD * 2);
  _Float16* ffn216    = (_Float16*)alloc((size_t)4 * DD * DD * 2);
  float*    decWT     = (float*)alloc((size_t)LATD * DD * 4);
  float*    h         = (float*)alloc((size_t)RR * DD * 4);
  _Float16* xn16      = (_Float16*)alloc((size_t)RR * DD * 2);
  _Float16* u16       = (_Float16*)alloc((size_t)RR * DD * 2);
  float*    ar        = (float*)alloc((size_t)RR * FF * 4);
  float*    ai        = (float*)alloc((size_t)RR * FF * 4);
  float*    sp        = (float*)alloc((size_t)RR * 2 * FF * 4);
  float*    Ar        = (float*)alloc((size_t)RR * FF * 4);
  float*    Ai        = (float*)alloc((size_t)RR * FF * 4);
  float*    Yr        = (float*)alloc((size_t)RR * FF * 4);
  float*    Yi        = (float*)alloc((size_t)RR * FF * 4);
  float*    cr        = (float*)alloc((size_t)64 * BB * FF * 4);
  float*    ci        = (float*)alloc((size_t)64 * BB * FF * 4);
  _Float16* y16       = (_Float16*)alloc((size_t)RR * 2 * FF * 2);
  float*    yd        = (float*)alloc((size_t)RR * DD * 4);  // spec_out result; later concept
  _Float16* g116      = (_Float16*)alloc((size_t)RR * 4 * DD * 2);
  float*    params    = (float*)alloc((size_t)RR * 128 * 4);
  float*    klsum     = (float*)alloc(256);

  auto cvt = [&](const float* src, _Float16* dst, size_t n) {
    int n4 = (int)(n / 4);
    int grid = (n4 + 255) / 256;
    cvt_kernel<<<grid, 256, 0, stream>>>(src, dst, n4);
  };

  // upfront conversions + embedding + kl zero
  cvt(emb, emb16, (size_t)VV * DD);
  cvt(enc_W, enc16, (size_t)128 * DD);
  transpose_decW<<<(LATD * DD) / 256, 256, 0, stream>>>(dec_W, decWT);
  embed_kernel<<<RR, 256, 0, stream>>>(x, emb, h);
  hipMemsetAsync(klsum, 0, sizeof(float), stream);

  for (int i = 0; i < NLAYER; ++i) {
    // per-layer weight conversions
    cvt(gate_W  + (size_t)i * DD * DD,        gate16,    (size_t)DD * DD);
    cvt(ogate_W + (size_t)i * DD * DD,        ogate16,   (size_t)DD * DD);
    cvt(decay_W + (size_t)i * FF * DD,        decay16,   (size_t)FF * DD);
    cvt(spec_in_W  + (size_t)i * 2 * FF * DD, specin16,  (size_t)2 * FF * DD);
    cvt(spec_out_W + (size_t)i * DD * 2 * FF, specout16, (size_t)DD * 2 * FF);
    cvt(ffn_W1 + (size_t)i * 4 * DD * DD,     ffn116,    (size_t)4 * DD * DD);
    cvt(ffn_W2 + (size_t)i * 4 * DD * DD,     ffn216,    (size_t)4 * DD * DD);

    // xn = LN(h)
    ln_kernel<<<RR, 256, 0, stream>>>(h, nullptr, norm1_g + i * DD, norm1_b + i * DD, xn16);
    // u = xn * sigmoid(xn @ gate_W^T + gate_b)
    gemm_nt<EP_GATE><<<dim3(DD / 128, RR / 128), 256, 0, stream>>>(
        xn16, gate16, RR, DD, DD, gate_b + i * DD, nullptr, nullptr, nullptr, xn16, u16);
    // decay -> a_r, a_i
    gemm_nt<EP_DECAY><<<dim3(FF / 128, RR / 128), 256, 0, stream>>>(
        u16, decay16, RR, FF, DD, decay_b + i * FF, ar, ai, freq + i * FF, nullptr, nullptr);
    // sp = u @ spec_in_W^T
    gemm_nt<EP_F32><<<dim3(2 * FF / 128, RR / 128), 256, 0, stream>>>(
        u16, specin16, RR, 2 * FF, DD, nullptr, sp, nullptr, nullptr, nullptr, nullptr);
    // chunked complex scan
    scan_phase1<<<64, 256, 0, stream>>>(ar, ai, sp, Ar, Ai, Yr, Yi);
    scan_phase2<<<2, 256, 0, stream>>>(Ar, Ai, Yr, Yi, cr, ci);
    scan_phase3<<<RR, 256, 0, stream>>>(Ar, Ai, Yr, Yi, cr, ci, y16);
    // yd = [y_r|y_i] @ spec_out_W^T
    gemm_nt<EP_F32><<<dim3(DD / 128, RR / 128), 256, 0, stream>>>(
        y16, specout16, RR, DD, 2 * FF, nullptr, yd, nullptr, nullptr, nullptr, nullptr);
    // h += yd * sigmoid(xn @ ogate_W^T + ogate_b)
    gemm_nt<EP_OGATE><<<dim3(DD / 128, RR / 128), 256, 0, stream>>>(
        xn16, ogate16, RR, DD, DD, ogate_b + i * DD, h, nullptr, yd, nullptr, nullptr);
    // f = LN(h); g1 = gelu(f @ W1^T + b1); h += g1 @ W2^T + b2
    ln_kernel<<<RR, 256, 0, stream>>>(h, nullptr, ffn_g + i * DD, ffn_b + i * DD, xn16);
    gemm_nt<EP_GELU16><<<dim3(4 * DD / 128, RR / 128), 256, 0, stream>>>(
        xn16, ffn116, RR, 4 * DD, DD, ffn_b1 + i * 4 * DD, nullptr, nullptr, nullptr, nullptr, g116);
    gemm_nt<EP_ADDH><<<dim3(DD / 128, RR / 128), 256, 0, stream>>>(
        g116, ffn216, RR, DD, 4 * DD, ffn_b2 + i * DD, h, nullptr, nullptr, nullptr, nullptr);
  }

  // final: VIB head + logits
  ln_kernel<<<RR, 256, 0, stream>>>(h, nullptr, vib_g, vib_b, xn16);
  gemm_nt<EP_F32><<<dim3(128 / 128, RR / 128), 256, 0, stream>>>(
      xn16, enc16, RR, 128, DD, enc_b, params, nullptr, nullptr, nullptr, nullptr);
  dec_kernel<<<RR, 256, 0, stream>>>(params, decWT, dec_b, yd);   // yd := concept
  kl_kernel<<<256, 256, 0, stream>>>(params, klsum);
  ln_kernel<<<RR, 256, 0, stream>>>(h, yd, normf_g, normf_b, xn16);
  gemm_nt<EP_F32><<<dim3(VV / 128, RR / 128), 256, 0, stream>>>(
      xn16, emb16, RR, VV, DD, nullptr, logits, nullptr, nullptr, nullptr, nullptr);
  fin_kernel<<<1, 1, 0, stream>>>(klsum, logits + (size_t)RR * VV);
}